// Round 1
// baseline (952.995 us; speedup 1.0000x reference)
//
#include <hip/hip_runtime.h>
#include <hip/hip_bf16.h>

#define NRES 512
#define DDIM 128
#define HDIM 128
#define NPOS (NRES * NRES)
#define EPSF 1e-5f
#define INV_SQRT_N 0.044194173824159216f   // 512^-0.5

typedef __attribute__((ext_vector_type(4))) float  floatx4;
typedef __attribute__((ext_vector_type(8))) short  shortx8;

__device__ __forceinline__ short f2bf(float f) {
    union { float f; unsigned u; } v; v.f = f;
    unsigned r = v.u + 0x7fffu + ((v.u >> 16) & 1u);   // RNE
    return (short)(r >> 16);
}
__device__ __forceinline__ float bf2f(short s) {
    union { unsigned u; float f; } v; v.u = ((unsigned)(unsigned short)s) << 16;
    return v.f;
}

// ---------------------------------------------------------------------------
// Kernel 1: fused LN(z) + 3 projections.
// Tile: 128 consecutive positions (one chunk of a row of the pair matrix).
// N looped over 5 chunks of 128 cols: chunks 0-3 = interleaved (w_ab_p, w_ab_g)
// rows so each h's p/gate land in adjacent output cols; chunk 4 = w_g -> g out.
// a_t/b_t written transposed: [h][pos] bf16 (K-contiguous for the triangle GEMM).
// ---------------------------------------------------------------------------
__global__ __launch_bounds__(256)
void proj_kernel(const float* __restrict__ z, const float* __restrict__ mask,
                 const float* __restrict__ ln_w, const float* __restrict__ ln_b,
                 const float* __restrict__ w_ab_p, const float* __restrict__ b_ab_p,
                 const float* __restrict__ w_ab_g, const float* __restrict__ b_ab_g,
                 const float* __restrict__ w_g,
                 float* __restrict__ g_out,
                 short* __restrict__ a_t, short* __restrict__ b_t)
{
    __shared__ short Az[128][136];     // zl bf16 tile, pad -> row stride 272B (16B mult)
    __shared__ short Bw[128][136];     // weight chunk bf16
    __shared__ short stage[64][136];   // [h_loc][pos] staging for transposed a/b writes
    __shared__ float mrow[128];

    const int tid  = threadIdx.x;
    const int lane = tid & 63;
    const int wave = tid >> 6;
    const int pos0 = blockIdx.x * 128;

    // ---- load z tile + LayerNorm -> Az (bf16) ----
    {
        const int r  = tid >> 1;
        const int hf = tid & 1;
        const float* zp = z + (size_t)(pos0 + r) * DDIM + hf * 64;
        float s = 0.f, sq = 0.f;
        #pragma unroll
        for (int c = 0; c < 16; ++c) {
            float4 v = ((const float4*)zp)[c];
            s  += v.x + v.y + v.z + v.w;
            sq += v.x*v.x + v.y*v.y + v.z*v.z + v.w*v.w;
        }
        s  += __shfl_xor(s, 1);
        sq += __shfl_xor(sq, 1);
        const float mean = s * (1.f/128.f);
        const float var  = sq * (1.f/128.f) - mean * mean;
        const float inv  = rsqrtf(var + EPSF);
        #pragma unroll
        for (int c = 0; c < 16; ++c) {
            float4 v = ((const float4*)zp)[c];
            const int d = hf*64 + c*4;
            short4 o;
            o.x = f2bf((v.x - mean)*inv*ln_w[d+0] + ln_b[d+0]);
            o.y = f2bf((v.y - mean)*inv*ln_w[d+1] + ln_b[d+1]);
            o.z = f2bf((v.z - mean)*inv*ln_w[d+2] + ln_b[d+2]);
            o.w = f2bf((v.w - mean)*inv*ln_w[d+3] + ln_b[d+3]);
            *(short4*)&Az[r][d] = o;
        }
        if (tid < 128) mrow[tid] = mask[pos0 + tid] * INV_SQRT_N;
    }

    const int lrow = lane & 15;
    const int quad = lane >> 4;
    const int mrow_base = wave * 32;

    for (int nc = 0; nc < 5; ++nc) {
        // ---- load weight chunk -> Bw (fp32 -> bf16) ----
        {
            const int c_loc = tid >> 1;
            const int hf    = tid & 1;
            const float* src;
            if (nc == 4) {
                src = w_g + (size_t)c_loc * DDIM;
            } else {
                const int c_glob = nc * 128 + c_loc;
                const int pp = c_glob >> 1;                 // weight/bias row
                src = ((c_glob & 1) ? w_ab_g : w_ab_p) + (size_t)pp * DDIM;
            }
            src += hf * 64;
            #pragma unroll
            for (int c = 0; c < 16; ++c) {
                float4 v = ((const float4*)src)[c];
                short4 o;
                o.x = f2bf(v.x); o.y = f2bf(v.y); o.z = f2bf(v.z); o.w = f2bf(v.w);
                *(short4*)&Bw[c_loc][hf*64 + c*4] = o;
            }
        }
        __syncthreads();   // Bw ready; prev-iter stage reads done

        // ---- MFMA: 128(pos) x 128(chunk cols), K=128 ----
        floatx4 acc[2][8];
        #pragma unroll
        for (int mi = 0; mi < 2; ++mi)
            #pragma unroll
            for (int ni = 0; ni < 8; ++ni)
                acc[mi][ni] = (floatx4){0.f, 0.f, 0.f, 0.f};

        #pragma unroll
        for (int ks = 0; ks < 4; ++ks) {
            shortx8 af0 = *(const shortx8*)&Az[mrow_base      + lrow][ks*32 + quad*8];
            shortx8 af1 = *(const shortx8*)&Az[mrow_base + 16 + lrow][ks*32 + quad*8];
            #pragma unroll
            for (int ni = 0; ni < 8; ++ni) {
                shortx8 bf = *(const shortx8*)&Bw[ni*16 + lrow][ks*32 + quad*8];
                acc[0][ni] = __builtin_amdgcn_mfma_f32_16x16x32_bf16(af0, bf, acc[0][ni], 0, 0, 0);
                acc[1][ni] = __builtin_amdgcn_mfma_f32_16x16x32_bf16(af1, bf, acc[1][ni], 0, 0, 0);
            }
        }

        if (nc == 4) {
            // g output: direct fp32 stores
            #pragma unroll
            for (int mi = 0; mi < 2; ++mi)
                #pragma unroll
                for (int ni = 0; ni < 8; ++ni)
                    #pragma unroll
                    for (int r = 0; r < 4; ++r) {
                        const int row = mrow_base + mi*16 + quad*4 + r;
                        const int col = ni*16 + lrow;
                        g_out[(size_t)(pos0 + row) * DDIM + col] = acc[mi][ni][r];
                    }
            __syncthreads();
        } else {
            // epilogue: combine p (even col) with sigmoid(gate) (odd col)
            #pragma unroll
            for (int mi = 0; mi < 2; ++mi) {
                #pragma unroll
                for (int ni = 0; ni < 8; ++ni) {
                    const int c_loc = ni*16 + lrow;
                    const int pp = (nc * 128 + c_loc) >> 1;
                    const float bp = b_ab_p[pp];
                    const float bg = b_ab_g[pp];
                    #pragma unroll
                    for (int r = 0; r < 4; ++r) {
                        const float v = acc[mi][ni][r];
                        const float partner = __shfl_xor(v, 1);
                        if ((lane & 1) == 0) {
                            const int row = mrow_base + mi*16 + quad*4 + r;
                            const float sig = 1.f / (1.f + __expf(-(partner + bg)));
                            const float val = (v + bp) * sig * mrow[row];
                            stage[c_loc >> 1][row] = f2bf(val);
                        }
                    }
                }
            }
            __syncthreads();   // stage complete
            // transposed writeout: [h][pos] contiguous 64B per thread
            short* dst = (nc < 2) ? a_t : b_t;
            const int h = ((nc & 1) << 6) + (tid >> 2);
            const int q = tid & 3;
            const short* sp = &stage[tid >> 2][q * 32];
            short* gp = dst + (size_t)h * NPOS + pos0 + q * 32;
            #pragma unroll
            for (int c = 0; c < 4; ++c)
                ((int4*)gp)[c] = ((const int4*)sp)[c];
        }
    }
}

// ---------------------------------------------------------------------------
// Kernel 2: triangle einsum — 128 batched per-h GEMMs, C = A * B^T, K=512.
// A = a_t[h] (512x512 bf16, K-contiguous), B = b_t[h]. Output xr[h][i][j] bf16.
// ---------------------------------------------------------------------------
__global__ __launch_bounds__(256)
void tri_kernel(const short* __restrict__ a_t, const short* __restrict__ b_t,
                short* __restrict__ xr)
{
    __shared__ short As[128][72];   // BK=64, row stride 144B (16B mult)
    __shared__ short Bs[128][72];

    const int tid  = threadIdx.x;
    const int lane = tid & 63;
    const int wave = tid >> 6;
    const int i0 = blockIdx.x * 128;
    const int j0 = blockIdx.y * 128;
    const int h  = blockIdx.z;
    const short* A = a_t + (size_t)h * NPOS;
    const short* B = b_t + (size_t)h * NPOS;

    floatx4 acc[2][8];
    #pragma unroll
    for (int mi = 0; mi < 2; ++mi)
        #pragma unroll
        for (int ni = 0; ni < 8; ++ni)
            acc[mi][ni] = (floatx4){0.f, 0.f, 0.f, 0.f};

    const int lr = tid >> 1;
    const int lh = tid & 1;
    const int lrow = lane & 15;
    const int quad = lane >> 4;

    for (int k0 = 0; k0 < NRES; k0 += 64) {
        const short* pa = A + (size_t)(i0 + lr) * NRES + k0 + lh * 32;
        const short* pb = B + (size_t)(j0 + lr) * NRES + k0 + lh * 32;
        #pragma unroll
        for (int c = 0; c < 4; ++c) {
            *(int4*)&As[lr][lh*32 + c*8] = ((const int4*)pa)[c];
            *(int4*)&Bs[lr][lh*32 + c*8] = ((const int4*)pb)[c];
        }
        __syncthreads();
        #pragma unroll
        for (int ks = 0; ks < 2; ++ks) {
            shortx8 af0 = *(const shortx8*)&As[wave*32      + lrow][ks*32 + quad*8];
            shortx8 af1 = *(const shortx8*)&As[wave*32 + 16 + lrow][ks*32 + quad*8];
            #pragma unroll
            for (int ni = 0; ni < 8; ++ni) {
                shortx8 bf = *(const shortx8*)&Bs[ni*16 + lrow][ks*32 + quad*8];
                acc[0][ni] = __builtin_amdgcn_mfma_f32_16x16x32_bf16(af0, bf, acc[0][ni], 0, 0, 0);
                acc[1][ni] = __builtin_amdgcn_mfma_f32_16x16x32_bf16(af1, bf, acc[1][ni], 0, 0, 0);
            }
        }
        __syncthreads();
    }

    short* xp = xr + (size_t)h * NPOS;
    #pragma unroll
    for (int mi = 0; mi < 2; ++mi)
        #pragma unroll
        for (int ni = 0; ni < 8; ++ni)
            #pragma unroll
            for (int r = 0; r < 4; ++r) {
                const int row = wave*32 + mi*16 + quad*4 + r;
                const int col = ni*16 + lrow;
                xp[(size_t)(i0 + row) * NRES + j0 + col] = f2bf(acc[mi][ni][r]);
            }
}

// ---------------------------------------------------------------------------
// Kernel 3: gather h-planes for a 128-pos tile, LN over h, project with w_z.
// ---------------------------------------------------------------------------
__global__ __launch_bounds__(256)
void out_kernel(const short* __restrict__ xr,
                const float* __restrict__ ln_w, const float* __restrict__ ln_b,
                const float* __restrict__ w_z, float* __restrict__ x_out)
{
    __shared__ float xt[128][130];    // [h][pos] fp32
    __shared__ short xln[128][136];   // [pos][h] bf16 (MFMA A tile)
    __shared__ short Bw[128][136];    // w_z bf16 [d][h]
    __shared__ float red_s[2][128];
    __shared__ float red_q[2][128];
    __shared__ float mean_l[128];
    __shared__ float inv_l[128];

    const int tid  = threadIdx.x;
    const int lane = tid & 63;
    const int wave = tid >> 6;
    const int pos0 = blockIdx.x * 128;

    // ---- load xr tile (bf16 -> fp32) and w_z (fp32 -> bf16) ----
    {
        const int hr = tid >> 1;
        const int hf = tid & 1;
        const short* sp = xr + (size_t)hr * NPOS + pos0 + hf * 64;
        #pragma unroll
        for (int c = 0; c < 8; ++c) {
            shortx8 v = ((const shortx8*)sp)[c];
            #pragma unroll
            for (int j = 0; j < 8; ++j)
                xt[hr][hf*64 + c*8 + j] = bf2f(v[j]);
        }
        const float* wp = w_z + (size_t)hr * HDIM + hf * 64;
        #pragma unroll
        for (int c = 0; c < 16; ++c) {
            float4 v = ((const float4*)wp)[c];
            short4 o;
            o.x = f2bf(v.x); o.y = f2bf(v.y); o.z = f2bf(v.z); o.w = f2bf(v.w);
            *(short4*)&Bw[hr][hf*64 + c*4] = o;
        }
    }
    __syncthreads();

    // ---- stats over h (2 threads per position) ----
    {
        const int p  = tid & 127;
        const int hf = tid >> 7;
        float s = 0.f, sq = 0.f;
        for (int hh = hf*64; hh < hf*64 + 64; ++hh) {
            const float v = xt[hh][p];
            s += v; sq += v * v;
        }
        red_s[hf][p] = s;
        red_q[hf][p] = sq;
    }
    __syncthreads();
    if (tid < 128) {
        const float s  = red_s[0][tid] + red_s[1][tid];
        const float sq = red_q[0][tid] + red_q[1][tid];
        const float mean = s * (1.f/128.f);
        const float var  = sq * (1.f/128.f) - mean * mean;
        mean_l[tid] = mean;
        inv_l[tid]  = rsqrtf(var + EPSF);
    }
    __syncthreads();

    // ---- normalize -> xln (bf16, [pos][h]) ----
    {
        const int p  = tid & 127;
        const int hf = tid >> 7;
        const float mean = mean_l[p];
        const float inv  = inv_l[p];
        for (int hh = hf*64; hh < hf*64 + 64; hh += 2) {
            short2 o;
            o.x = f2bf((xt[hh  ][p] - mean) * inv * ln_w[hh  ] + ln_b[hh  ]);
            o.y = f2bf((xt[hh+1][p] - mean) * inv * ln_w[hh+1] + ln_b[hh+1]);
            *(short2*)&xln[p][hh] = o;
        }
    }
    __syncthreads();

    // ---- MFMA: out[pos][d] = sum_h xln[pos][h] * w_z[d][h] ----
    floatx4 acc[2][8];
    #pragma unroll
    for (int mi = 0; mi < 2; ++mi)
        #pragma unroll
        for (int ni = 0; ni < 8; ++ni)
            acc[mi][ni] = (floatx4){0.f, 0.f, 0.f, 0.f};

    const int lrow = lane & 15;
    const int quad = lane >> 4;
    #pragma unroll
    for (int ks = 0; ks < 4; ++ks) {
        shortx8 af0 = *(const shortx8*)&xln[wave*32      + lrow][ks*32 + quad*8];
        shortx8 af1 = *(const shortx8*)&xln[wave*32 + 16 + lrow][ks*32 + quad*8];
        #pragma unroll
        for (int ni = 0; ni < 8; ++ni) {
            shortx8 bf = *(const shortx8*)&Bw[ni*16 + lrow][ks*32 + quad*8];
            acc[0][ni] = __builtin_amdgcn_mfma_f32_16x16x32_bf16(af0, bf, acc[0][ni], 0, 0, 0);
            acc[1][ni] = __builtin_amdgcn_mfma_f32_16x16x32_bf16(af1, bf, acc[1][ni], 0, 0, 0);
        }
    }
    #pragma unroll
    for (int mi = 0; mi < 2; ++mi)
        #pragma unroll
        for (int ni = 0; ni < 8; ++ni)
            #pragma unroll
            for (int r = 0; r < 4; ++r) {
                const int row = wave*32 + mi*16 + quad*4 + r;
                const int col = ni*16 + lrow;
                x_out[(size_t)(pos0 + row) * DDIM + col] = acc[mi][ni][r];
            }
}

extern "C" void kernel_launch(void* const* d_in, const int* in_sizes, int n_in,
                              void* d_out, int out_size, void* d_ws, size_t ws_size,
                              hipStream_t stream)
{
    const float* z        = (const float*)d_in[0];
    const float* mask     = (const float*)d_in[1];
    const float* ln_in_w  = (const float*)d_in[2];
    const float* ln_in_b  = (const float*)d_in[3];
    const float* w_ab_p   = (const float*)d_in[4];
    const float* b_ab_p   = (const float*)d_in[5];
    const float* w_ab_g   = (const float*)d_in[6];
    const float* b_ab_g   = (const float*)d_in[7];
    const float* w_g      = (const float*)d_in[8];
    const float* ln_out_w = (const float*)d_in[9];
    const float* ln_out_b = (const float*)d_in[10];
    const float* w_z      = (const float*)d_in[11];

    float* x_out = (float*)d_out;
    float* g_out = x_out + (size_t)NPOS * DDIM;

    // workspace: a_t (64MB) | b_t (64MB) | xr (64MB), all bf16 [H][NPOS]
    short* a_t = (short*)d_ws;
    short* b_t = a_t + (size_t)HDIM * NPOS;
    short* xr  = b_t + (size_t)HDIM * NPOS;

    proj_kernel<<<NPOS/128, 256, 0, stream>>>(z, mask, ln_in_w, ln_in_b,
                                              w_ab_p, b_ab_p, w_ab_g, b_ab_g,
                                              w_g, g_out, a_t, b_t);
    tri_kernel<<<dim3(4, 4, 128), 256, 0, stream>>>(a_t, b_t, xr);
    out_kernel<<<NPOS/128, 256, 0, stream>>>(xr, ln_out_w, ln_out_b, w_z, x_out);
}

// Round 3
// 735.977 us; speedup vs baseline: 1.2949x; 1.2949x over previous
//
#include <hip/hip_runtime.h>
#include <hip/hip_bf16.h>

#define NRES 512
#define DDIM 128
#define HDIM 128
#define NPOS (NRES * NRES)
#define PLANE ((size_t)HDIM * NPOS)
#define EPSF 1e-5f
#define INV_SQRT_N 0.044194173824159216f   // 512^-0.5

typedef __attribute__((ext_vector_type(4))) float  floatx4;
typedef __attribute__((ext_vector_type(8))) short  shortx8;

__device__ __forceinline__ short f2bf(float f) {
    union { float f; unsigned u; } v; v.f = f;
    unsigned r = v.u + 0x7fffu + ((v.u >> 16) & 1u);   // RNE
    return (short)(r >> 16);
}
__device__ __forceinline__ float bf2f(short s) {
    union { unsigned u; float f; } v; v.u = ((unsigned)(unsigned short)s) << 16;
    return v.f;
}

// ---------------------------------------------------------------------------
// Kernel 0: pack projection weights as bf16 in MFMA B-fragment lane order.
// Layout: pair [group(2)][chunk(2)][phase(2:p,g)][ni(4)][ks(4)][lane(64)][8]
//         then w_g  [chunk(2)][ni(4)][ks(4)][lane(64)][8]
// element: h = base + ni*16 + (lane&15), k = ks*32 + (lane>>4)*8 + j
// ---------------------------------------------------------------------------
__global__ __launch_bounds__(256)
void prep_kernel(const float* __restrict__ wabp, const float* __restrict__ wabg,
                 const float* __restrict__ wg, short* __restrict__ wpk)
{
    const int i = blockIdx.x * 256 + threadIdx.x;   // < 81920
    float v;
    if (i < 65536) {
        const int j = i & 7, lane = (i >> 3) & 63, ks = (i >> 9) & 3, ni = (i >> 11) & 3;
        const int phase = (i >> 13) & 1, c = (i >> 14) & 1, grp = (i >> 15) & 1;
        const int h = grp * 128 + c * 64 + ni * 16 + (lane & 15);
        const int k = ks * 32 + ((lane >> 4) & 3) * 8 + j;
        v = (phase ? wabg : wabp)[h * 128 + k];
    } else {
        const int ii = i - 65536;
        const int j = ii & 7, lane = (ii >> 3) & 63, ks = (ii >> 9) & 3, ni = (ii >> 11) & 3;
        const int c = (ii >> 13) & 1;
        const int h = c * 64 + ni * 16 + (lane & 15);
        const int k = ks * 32 + ((lane >> 4) & 3) * 8 + j;
        v = wg[h * 128 + k];
    }
    wpk[i] = f2bf(v);
}

// ---------------------------------------------------------------------------
// Kernel 1: LayerNorm(z) -> zl bf16 [NPOS][128]
// ---------------------------------------------------------------------------
__global__ __launch_bounds__(256)
void ln_kernel(const float* __restrict__ z, const float* __restrict__ lw,
               const float* __restrict__ lb, short* __restrict__ zl)
{
    const int tid = threadIdx.x;
    const int r = tid >> 1, hf = tid & 1;
    const size_t row = (size_t)blockIdx.x * 128 + r;
    const float* zp = z + row * DDIM + hf * 64;
    float4 v[16];
    float s = 0.f, sq = 0.f;
    #pragma unroll
    for (int c = 0; c < 16; ++c) {
        v[c] = ((const float4*)zp)[c];
        s  += v[c].x + v[c].y + v[c].z + v[c].w;
        sq += v[c].x*v[c].x + v[c].y*v[c].y + v[c].z*v[c].z + v[c].w*v[c].w;
    }
    s  += __shfl_xor(s, 1);
    sq += __shfl_xor(sq, 1);
    const float mean = s * (1.f/128.f);
    const float var  = sq * (1.f/128.f) - mean * mean;
    const float inv  = rsqrtf(var + EPSF);
    short* op = zl + row * DDIM + hf * 64;
    #pragma unroll
    for (int c = 0; c < 16; ++c) {
        const int d = hf*64 + c*4;
        short4 o;
        o.x = f2bf((v[c].x - mean)*inv*lw[d+0] + lb[d+0]);
        o.y = f2bf((v[c].y - mean)*inv*lw[d+1] + lb[d+1]);
        o.z = f2bf((v[c].z - mean)*inv*lw[d+2] + lb[d+2]);
        o.w = f2bf((v[c].w - mean)*inv*lw[d+3] + lb[d+3]);
        *(short4*)(op + c*4) = o;
    }
}

// ---------------------------------------------------------------------------
// Kernel 2: projections. grid (6 chunks, 2048 pos-tiles).
// chunk 0,1: a (h 0..63 / 64..127); 2,3: b; 4,5: w_g halves -> g out.
// A-frags direct from global zl; B-frags direct from packed bf16 weights.
// ---------------------------------------------------------------------------
__global__ __launch_bounds__(256)
void proj_kernel(const short* __restrict__ zl, const float* __restrict__ mask,
                 const short* __restrict__ wpk,
                 const float* __restrict__ b_ab_p, const float* __restrict__ b_ab_g,
                 float* __restrict__ g_out,
                 short* __restrict__ a_t, short* __restrict__ b_t)
{
    __shared__ short stage[64][136];
    const int tid = threadIdx.x, lane = tid & 63, wave = tid >> 6;
    const int lrow = lane & 15, quad = lane >> 4;
    const int chunk = blockIdx.x;
    const int pos0  = blockIdx.y * 128;

    shortx8 af[2][4];
    #pragma unroll
    for (int mi = 0; mi < 2; ++mi) {
        const short* ap = zl + (size_t)(pos0 + wave*32 + mi*16 + lrow) * DDIM + quad*8;
        #pragma unroll
        for (int ks = 0; ks < 4; ++ks)
            af[mi][ks] = *(const shortx8*)(ap + ks*32);
    }

    if (chunk < 4) {
        const int grp = chunk >> 1, c = chunk & 1;
        const short* pb = wpk + (size_t)((grp*2 + c)*2    ) * 8192 + lane*8;
        const short* gb = wpk + (size_t)((grp*2 + c)*2 + 1) * 8192 + lane*8;
        floatx4 accp[2][4], accg[2][4];
        #pragma unroll
        for (int mi = 0; mi < 2; ++mi)
            #pragma unroll
            for (int ni = 0; ni < 4; ++ni) {
                accp[mi][ni] = (floatx4){0.f,0.f,0.f,0.f};
                accg[mi][ni] = (floatx4){0.f,0.f,0.f,0.f};
            }
        #pragma unroll
        for (int ks = 0; ks < 4; ++ks)
            #pragma unroll
            for (int ni = 0; ni < 4; ++ni) {
                shortx8 bp = *(const shortx8*)(pb + (ni*4 + ks)*512);
                accp[0][ni] = __builtin_amdgcn_mfma_f32_16x16x32_bf16(af[0][ks], bp, accp[0][ni], 0,0,0);
                accp[1][ni] = __builtin_amdgcn_mfma_f32_16x16x32_bf16(af[1][ks], bp, accp[1][ni], 0,0,0);
                shortx8 bg = *(const shortx8*)(gb + (ni*4 + ks)*512);
                accg[0][ni] = __builtin_amdgcn_mfma_f32_16x16x32_bf16(af[0][ks], bg, accg[0][ni], 0,0,0);
                accg[1][ni] = __builtin_amdgcn_mfma_f32_16x16x32_bf16(af[1][ks], bg, accg[1][ni], 0,0,0);
            }
        const int hb0 = grp*128 + c*64;
        #pragma unroll
        for (int mi = 0; mi < 2; ++mi) {
            float mv[4];
            #pragma unroll
            for (int r = 0; r < 4; ++r)
                mv[r] = mask[pos0 + wave*32 + mi*16 + quad*4 + r] * INV_SQRT_N;
            #pragma unroll
            for (int ni = 0; ni < 4; ++ni) {
                const int col = ni*16 + lrow;
                const float bp = b_ab_p[hb0 + col];
                const float bg = b_ab_g[hb0 + col];
                #pragma unroll
                for (int r = 0; r < 4; ++r) {
                    const int row = wave*32 + mi*16 + quad*4 + r;
                    const float sig = 1.f / (1.f + __expf(-(accg[mi][ni][r] + bg)));
                    stage[col][row] = f2bf((accp[mi][ni][r] + bp) * sig * mv[r]);
                }
            }
        }
        __syncthreads();
        short* dst = ((grp == 0) ? a_t : b_t)
                   + (size_t)(c*64 + (tid >> 2)) * NPOS + pos0 + (tid & 3) * 32;
        const short* sp = &stage[tid >> 2][(tid & 3) * 32];
        #pragma unroll
        for (int q = 0; q < 4; ++q)
            ((int4*)dst)[q] = ((const int4*)sp)[q];
    } else {
        const int c = chunk - 4;
        const short* gg = wpk + 65536 + (size_t)c * 8192 + lane*8;
        floatx4 acc[2][4];
        #pragma unroll
        for (int mi = 0; mi < 2; ++mi)
            #pragma unroll
            for (int ni = 0; ni < 4; ++ni)
                acc[mi][ni] = (floatx4){0.f,0.f,0.f,0.f};
        #pragma unroll
        for (int ks = 0; ks < 4; ++ks)
            #pragma unroll
            for (int ni = 0; ni < 4; ++ni) {
                shortx8 bw = *(const shortx8*)(gg + (ni*4 + ks)*512);
                acc[0][ni] = __builtin_amdgcn_mfma_f32_16x16x32_bf16(af[0][ks], bw, acc[0][ni], 0,0,0);
                acc[1][ni] = __builtin_amdgcn_mfma_f32_16x16x32_bf16(af[1][ks], bw, acc[1][ni], 0,0,0);
            }
        #pragma unroll
        for (int mi = 0; mi < 2; ++mi)
            #pragma unroll
            for (int ni = 0; ni < 4; ++ni)
                #pragma unroll
                for (int r = 0; r < 4; ++r) {
                    const int row = wave*32 + mi*16 + quad*4 + r;
                    g_out[(size_t)(pos0 + row) * DDIM + c*64 + ni*16 + lrow] = acc[mi][ni][r];
                }
    }
}

// ---------------------------------------------------------------------------
// Kernel 3: triangle einsum — round-1-verbatim proven version.
// 128 batched per-h GEMMs, C = A * B^T, K=512, padded LDS vector staging.
// ---------------------------------------------------------------------------
__global__ __launch_bounds__(256)
void tri_kernel(const short* __restrict__ a_t, const short* __restrict__ b_t,
                short* __restrict__ xr)
{
    __shared__ short As[128][72];   // BK=64, row stride 144B (16B mult)
    __shared__ short Bs[128][72];

    const int tid  = threadIdx.x;
    const int lane = tid & 63;
    const int wave = tid >> 6;
    const int i0 = blockIdx.x * 128;
    const int j0 = blockIdx.y * 128;
    const int h  = blockIdx.z;
    const short* A = a_t + (size_t)h * NPOS;
    const short* B = b_t + (size_t)h * NPOS;

    floatx4 acc[2][8];
    #pragma unroll
    for (int mi = 0; mi < 2; ++mi)
        #pragma unroll
        for (int ni = 0; ni < 8; ++ni)
            acc[mi][ni] = (floatx4){0.f, 0.f, 0.f, 0.f};

    const int lr = tid >> 1;
    const int lh = tid & 1;
    const int lrow = lane & 15;
    const int quad = lane >> 4;

    for (int k0 = 0; k0 < NRES; k0 += 64) {
        const short* pa = A + (size_t)(i0 + lr) * NRES + k0 + lh * 32;
        const short* pb = B + (size_t)(j0 + lr) * NRES + k0 + lh * 32;
        #pragma unroll
        for (int c = 0; c < 4; ++c) {
            *(int4*)&As[lr][lh*32 + c*8] = ((const int4*)pa)[c];
            *(int4*)&Bs[lr][lh*32 + c*8] = ((const int4*)pb)[c];
        }
        __syncthreads();
        #pragma unroll
        for (int ks = 0; ks < 2; ++ks) {
            shortx8 af0 = *(const shortx8*)&As[wave*32      + lrow][ks*32 + quad*8];
            shortx8 af1 = *(const shortx8*)&As[wave*32 + 16 + lrow][ks*32 + quad*8];
            #pragma unroll
            for (int ni = 0; ni < 8; ++ni) {
                shortx8 bf = *(const shortx8*)&Bs[ni*16 + lrow][ks*32 + quad*8];
                acc[0][ni] = __builtin_amdgcn_mfma_f32_16x16x32_bf16(af0, bf, acc[0][ni], 0, 0, 0);
                acc[1][ni] = __builtin_amdgcn_mfma_f32_16x16x32_bf16(af1, bf, acc[1][ni], 0, 0, 0);
            }
        }
        __syncthreads();
    }

    short* xp = xr + (size_t)h * NPOS;
    #pragma unroll
    for (int mi = 0; mi < 2; ++mi)
        #pragma unroll
        for (int ni = 0; ni < 8; ++ni)
            #pragma unroll
            for (int r = 0; r < 4; ++r) {
                const int row = wave*32 + mi*16 + quad*4 + r;
                const int col = ni*16 + lrow;
                xp[(size_t)(i0 + row) * NRES + j0 + col] = f2bf(acc[mi][ni][r]);
            }
}

// ---------------------------------------------------------------------------
// Kernel 4: gather h-planes for a 128-pos tile, LN over h, project with w_z.
// ---------------------------------------------------------------------------
__global__ __launch_bounds__(256)
void out_kernel(const short* __restrict__ xr,
                const float* __restrict__ ln_w, const float* __restrict__ ln_b,
                const float* __restrict__ w_z, float* __restrict__ x_out)
{
    __shared__ float xt[128][130];    // [h][pos] fp32
    __shared__ short xln[128][136];   // [pos][h] bf16 (MFMA A tile)
    __shared__ short Bw[128][136];    // w_z bf16 [d][h]
    __shared__ float red_s[2][128];
    __shared__ float red_q[2][128];
    __shared__ float mean_l[128];
    __shared__ float inv_l[128];

    const int tid  = threadIdx.x;
    const int lane = tid & 63;
    const int wave = tid >> 6;
    const int pos0 = blockIdx.x * 128;

    {
        const int hr = tid >> 1;
        const int hf = tid & 1;
        const short* sp = xr + (size_t)hr * NPOS + pos0 + hf * 64;
        #pragma unroll
        for (int c = 0; c < 8; ++c) {
            shortx8 v = ((const shortx8*)sp)[c];
            #pragma unroll
            for (int j = 0; j < 8; ++j)
                xt[hr][hf*64 + c*8 + j] = bf2f(v[j]);
        }
        const float* wp = w_z + (size_t)hr * HDIM + hf * 64;
        #pragma unroll
        for (int c = 0; c < 16; ++c) {
            float4 v = ((const float4*)wp)[c];
            short4 o;
            o.x = f2bf(v.x); o.y = f2bf(v.y); o.z = f2bf(v.z); o.w = f2bf(v.w);
            *(short4*)&Bw[hr][hf*64 + c*4] = o;
        }
    }
    __syncthreads();

    {
        const int p  = tid & 127;
        const int hf = tid >> 7;
        float s = 0.f, sq = 0.f;
        for (int hh = hf*64; hh < hf*64 + 64; ++hh) {
            const float v = xt[hh][p];
            s += v; sq += v * v;
        }
        red_s[hf][p] = s;
        red_q[hf][p] = sq;
    }
    __syncthreads();
    if (tid < 128) {
        const float s  = red_s[0][tid] + red_s[1][tid];
        const float sq = red_q[0][tid] + red_q[1][tid];
        const float mean = s * (1.f/128.f);
        const float var  = sq * (1.f/128.f) - mean * mean;
        mean_l[tid] = mean;
        inv_l[tid]  = rsqrtf(var + EPSF);
    }
    __syncthreads();

    {
        const int p  = tid & 127;
        const int hf = tid >> 7;
        const float mean = mean_l[p];
        const float inv  = inv_l[p];
        for (int hh = hf*64; hh < hf*64 + 64; hh += 2) {
            short2 o;
            o.x = f2bf((xt[hh  ][p] - mean) * inv * ln_w[hh  ] + ln_b[hh  ]);
            o.y = f2bf((xt[hh+1][p] - mean) * inv * ln_w[hh+1] + ln_b[hh+1]);
            *(short2*)&xln[p][hh] = o;
        }
    }
    __syncthreads();

    floatx4 acc[2][8];
    #pragma unroll
    for (int mi = 0; mi < 2; ++mi)
        #pragma unroll
        for (int ni = 0; ni < 8; ++ni)
            acc[mi][ni] = (floatx4){0.f,0.f,0.f,0.f};

    const int lrow = lane & 15;
    const int quad = lane >> 4;
    #pragma unroll
    for (int ks = 0; ks < 4; ++ks) {
        shortx8 af0 = *(const shortx8*)&xln[wave*32      + lrow][ks*32 + quad*8];
        shortx8 af1 = *(const shortx8*)&xln[wave*32 + 16 + lrow][ks*32 + quad*8];
        #pragma unroll
        for (int ni = 0; ni < 8; ++ni) {
            shortx8 bf = *(const shortx8*)&Bw[ni*16 + lrow][ks*32 + quad*8];
            acc[0][ni] = __builtin_amdgcn_mfma_f32_16x16x32_bf16(af0, bf, acc[0][ni], 0,0,0);
            acc[1][ni] = __builtin_amdgcn_mfma_f32_16x16x32_bf16(af1, bf, acc[1][ni], 0,0,0);
        }
    }
    #pragma unroll
    for (int mi = 0; mi < 2; ++mi)
        #pragma unroll
        for (int ni = 0; ni < 8; ++ni)
            #pragma unroll
            for (int r = 0; r < 4; ++r) {
                const int row = wave*32 + mi*16 + quad*4 + r;
                const int col = ni*16 + lrow;
                x_out[(size_t)(pos0 + row) * DDIM + col] = acc[mi][ni][r];
            }
}

extern "C" void kernel_launch(void* const* d_in, const int* in_sizes, int n_in,
                              void* d_out, int out_size, void* d_ws, size_t ws_size,
                              hipStream_t stream)
{
    const float* z        = (const float*)d_in[0];
    const float* mask     = (const float*)d_in[1];
    const float* ln_in_w  = (const float*)d_in[2];
    const float* ln_in_b  = (const float*)d_in[3];
    const float* w_ab_p   = (const float*)d_in[4];
    const float* b_ab_p   = (const float*)d_in[5];
    const float* w_ab_g   = (const float*)d_in[6];
    const float* b_ab_g   = (const float*)d_in[7];
    const float* w_g      = (const float*)d_in[8];
    const float* ln_out_w = (const float*)d_in[9];
    const float* ln_out_b = (const float*)d_in[10];
    const float* w_z      = (const float*)d_in[11];

    float* x_out = (float*)d_out;
    float* g_out = x_out + (size_t)NPOS * DDIM;

    // ws: a_t | b_t | zl (aliased with xr; zl dead before tri writes xr)
    short* a_t = (short*)d_ws;
    short* b_t = a_t + PLANE;
    short* zl  = b_t + PLANE;
    short* xr  = zl;
    // packed bf16 weights live in the x-output region of d_out until out_kernel
    // overwrites it (prep -> proj ordering is stream-serialized).
    short* wpk = (short*)x_out;

    prep_kernel<<<320, 256, 0, stream>>>(w_ab_p, w_ab_g, w_g, wpk);
    ln_kernel<<<NPOS/128, 256, 0, stream>>>(z, ln_in_w, ln_in_b, zl);
    proj_kernel<<<dim3(6, NPOS/128), 256, 0, stream>>>(zl, mask, wpk,
                                                       b_ab_p, b_ab_g,
                                                       g_out, a_t, b_t);
    tri_kernel<<<dim3(4, 4, 128), 256, 0, stream>>>(a_t, b_t, xr);
    out_kernel<<<NPOS/128, 256, 0, stream>>>(xr, ln_out_w, ln_out_b, w_z, x_out);
}